// Round 1
// baseline (771.692 us; speedup 1.0000x reference)
//
#include <hip/hip_runtime.h>
#include <hip/hip_bf16.h>
#include <math.h>

typedef unsigned short u16;
typedef unsigned int   u32;
typedef short bf16x8 __attribute__((ext_vector_type(8)));
typedef float f32x4  __attribute__((ext_vector_type(4)));

#define Bb 32
#define Tt 2048
#define Ee 1024
#define Mm (Bb*Tt)
// LDS row stride in bf16 elements (80 bytes): keeps ds_read_b128 frag reads at
// 2-way bank aliasing (free, m136) and 16B-aligned.
#define LSTR 40

__device__ __forceinline__ float tanh_fast(float x) {
  float ax = fminf(fabsf(x), 15.0f);
  float e  = __expf(2.0f * ax);
  float t  = 1.0f - 2.0f / (e + 1.0f);
  return copysignf(t, x);
}

// split two fp32 into packed bf16 hi-plane / lo-plane pairs (truncation split:
// hi = trunc16(a), lo = trunc16(a - hi); residual ~2^-16 relative)
__device__ __forceinline__ void cvt2(float a0, float a1, u32& hi, u32& lo) {
  u32 u0 = __float_as_uint(a0), u1 = __float_as_uint(a1);
  hi = (u0 >> 16) | (u1 & 0xffff0000u);
  float r0 = a0 - __uint_as_float(u0 & 0xffff0000u);
  float r1 = a1 - __uint_as_float(u1 & 0xffff0000u);
  lo = (__float_as_uint(r0) >> 16) | (__float_as_uint(r1) & 0xffff0000u);
}

// ---------------- K0: W (K x N fp32) -> Wt_hi/Wt_lo (N x K bf16) ----------------
__global__ __launch_bounds__(256) void wt_convert(const float* __restrict__ W,
                                                  u16* __restrict__ Wt_hi,
                                                  u16* __restrict__ Wt_lo) {
  __shared__ float tile[32][33];
  int n0 = blockIdx.x * 32, k0 = blockIdx.y * 32;
  int tx = threadIdx.x, ty = threadIdx.y;   // 32 x 8
#pragma unroll
  for (int i = 0; i < 4; ++i)
    tile[ty + 8*i][tx] = W[(size_t)(k0 + ty + 8*i) * Ee + n0 + tx];
  __syncthreads();
#pragma unroll
  for (int i = 0; i < 4; ++i) {
    float v = tile[tx][ty + 8*i];
    u32 u = __float_as_uint(v);
    u16 hi = (u16)(u >> 16);
    float rem = v - __uint_as_float(u & 0xffff0000u);
    u16 lo = (u16)(__float_as_uint(rem) >> 16);
    size_t idx = (size_t)(n0 + ty + 8*i) * Ee + k0 + tx;
    Wt_hi[idx] = hi;
    Wt_lo[idx] = lo;
  }
}

// ---------------- K1: ht = tanh(enc@W + b), fused score = ctx . ht ----------------
// 128x128 tile, BK=32, 4 waves each doing 4x4 of mfma_f32_16x16x32_bf16,
// split-bf16: acc += Ahi*Bhi + Ahi*Blo + Alo*Bhi
__global__ __launch_bounds__(256, 2) void gemm_tanh_score(
    const float* __restrict__ enc, const float* __restrict__ ctx,
    const float* __restrict__ bias,
    const u16* __restrict__ Wt_hi, const u16* __restrict__ Wt_lo,
    u16* __restrict__ ht, float* __restrict__ scores) {
  __shared__ u16 Ahi[128*LSTR], Alo[128*LSTR], Bhi[128*LSTR], Blo[128*LSTR];

  int bx = blockIdx.x;
  int nt = bx & 7, mt = bx >> 3;        // consecutive blocks share the M-panel (L3 reuse of enc)
  int m0 = mt * 128, n0 = nt * 128;
  int tid = threadIdx.x;
  int w = tid >> 6, lane = tid & 63;
  int wm = (w & 1) * 64, wn = (w >> 1) * 64;
  int q = lane >> 4, c = lane & 15;

  f32x4 zero = {0.f, 0.f, 0.f, 0.f};
  f32x4 acc[4][4];
#pragma unroll
  for (int i = 0; i < 4; ++i)
#pragma unroll
    for (int j = 0; j < 4; ++j) acc[i][j] = zero;

  // staging mapping: thread t -> row (t>>1) in [0,128), k-half (t&1)*16
  int ar = tid >> 1, ah = tid & 1;
  const float* Ap  = enc   + (size_t)(m0 + ar) * Ee + ah * 16;
  const u16*   BhP = Wt_hi + (size_t)(n0 + ar) * Ee + ah * 16;
  const u16*   BlP = Wt_lo + (size_t)(n0 + ar) * Ee + ah * 16;
  u16* AhiW = &Ahi[ar * LSTR + ah * 16];
  u16* AloW = &Alo[ar * LSTR + ah * 16];
  u16* BhiW = &Bhi[ar * LSTR + ah * 16];
  u16* BloW = &Blo[ar * LSTR + ah * 16];

  for (int kt = 0; kt < 32; ++kt) {
    // global prefetch into registers (independent of LDS)
    const float4* ap = (const float4*)(Ap + (size_t)kt * 32);
    float4 f0 = ap[0], f1 = ap[1], f2 = ap[2], f3 = ap[3];
    const uint4* bhp = (const uint4*)(BhP + (size_t)kt * 32);
    uint4 bH0 = bhp[0], bH1 = bhp[1];
    const uint4* blp = (const uint4*)(BlP + (size_t)kt * 32);
    uint4 bL0 = blp[0], bL1 = blp[1];

    u32 hi[8], lo[8];
    cvt2(f0.x, f0.y, hi[0], lo[0]); cvt2(f0.z, f0.w, hi[1], lo[1]);
    cvt2(f1.x, f1.y, hi[2], lo[2]); cvt2(f1.z, f1.w, hi[3], lo[3]);
    cvt2(f2.x, f2.y, hi[4], lo[4]); cvt2(f2.z, f2.w, hi[5], lo[5]);
    cvt2(f3.x, f3.y, hi[6], lo[6]); cvt2(f3.z, f3.w, hi[7], lo[7]);

    __syncthreads();   // previous iteration's frag reads complete
    ((uint4*)AhiW)[0] = make_uint4(hi[0], hi[1], hi[2], hi[3]);
    ((uint4*)AhiW)[1] = make_uint4(hi[4], hi[5], hi[6], hi[7]);
    ((uint4*)AloW)[0] = make_uint4(lo[0], lo[1], lo[2], lo[3]);
    ((uint4*)AloW)[1] = make_uint4(lo[4], lo[5], lo[6], lo[7]);
    ((uint4*)BhiW)[0] = bH0; ((uint4*)BhiW)[1] = bH1;
    ((uint4*)BloW)[0] = bL0; ((uint4*)BloW)[1] = bL1;
    __syncthreads();   // staging visible

    bf16x8 aH[4], aL[4], bH[4], bL[4];
#pragma unroll
    for (int i = 0; i < 4; ++i) {
      int rax = (wm + i * 16 + c) * LSTR + q * 8;
      aH[i] = *(const bf16x8*)(&Ahi[rax]);
      aL[i] = *(const bf16x8*)(&Alo[rax]);
      int rbx = (wn + i * 16 + c) * LSTR + q * 8;
      bH[i] = *(const bf16x8*)(&Bhi[rbx]);
      bL[i] = *(const bf16x8*)(&Blo[rbx]);
    }
#pragma unroll
    for (int i = 0; i < 4; ++i)
#pragma unroll
      for (int j = 0; j < 4; ++j) {
        acc[i][j] = __builtin_amdgcn_mfma_f32_16x16x32_bf16(aH[i], bH[j], acc[i][j], 0, 0, 0);
        acc[i][j] = __builtin_amdgcn_mfma_f32_16x16x32_bf16(aH[i], bL[j], acc[i][j], 0, 0, 0);
        acc[i][j] = __builtin_amdgcn_mfma_f32_16x16x32_bf16(aL[i], bH[j], acc[i][j], 0, 0, 0);
      }
  }

  // epilogue: z -> tanh -> store bf16 ht; fused score partial (ctx dot)
  int bidx = m0 >> 11;                   // T = 2048, tile rows share one batch index
  float ctxv[4], biasv[4];
#pragma unroll
  for (int j = 0; j < 4; ++j) {
    int col = n0 + wn + j * 16 + c;
    ctxv[j]  = ctx[bidx * Ee + col];
    biasv[j] = bias[col];
  }
#pragma unroll
  for (int i = 0; i < 4; ++i) {
#pragma unroll
    for (int r = 0; r < 4; ++r) {
      int rowG = m0 + wm + i * 16 + q * 4 + r;   // C/D: row=(lane>>4)*4+reg, col=lane&15
      u16* hrow = ht + (size_t)rowG * Ee + n0 + wn + c;
      float s = 0.f;
#pragma unroll
      for (int j = 0; j < 4; ++j) {
        float h = tanh_fast(acc[i][j][r] + biasv[j]);
        __hip_bfloat16 hb = __float2bfloat16(h);
        hrow[j * 16] = *(u16*)&hb;
        s += h * ctxv[j];
      }
      s += __shfl_xor(s, 1); s += __shfl_xor(s, 2);
      s += __shfl_xor(s, 4); s += __shfl_xor(s, 8);
      if (c == 0) atomicAdd(&scores[rowG], s);
    }
  }
}

// ---------------- K2: softmax over T per batch row ----------------
__global__ __launch_bounds__(256) void softmax_t(const float* __restrict__ scores,
                                                 float* __restrict__ at) {
  __shared__ float red[256];
  int b = blockIdx.x, tid = threadIdx.x;
  float v[8];
  float mx = -3.0e38f;
#pragma unroll
  for (int i = 0; i < 8; ++i) {
    v[i] = scores[b * Tt + i * 256 + tid];
    mx = fmaxf(mx, v[i]);
  }
  red[tid] = mx; __syncthreads();
  for (int s = 128; s > 0; s >>= 1) {
    if (tid < s) red[tid] = fmaxf(red[tid], red[tid + s]);
    __syncthreads();
  }
  mx = red[0]; __syncthreads();
  float sum = 0.f;
#pragma unroll
  for (int i = 0; i < 8; ++i) { v[i] = __expf(v[i] - mx); sum += v[i]; }
  red[tid] = sum; __syncthreads();
  for (int s = 128; s > 0; s >>= 1) {
    if (tid < s) red[tid] += red[tid + s];
    __syncthreads();
  }
  float inv = 1.0f / red[0];
#pragma unroll
  for (int i = 0; i < 8; ++i) at[b * Tt + i * 256 + tid] = v[i] * inv;
}

// ---------------- K3: out[b,e] = sum_t at[b,t] * ht[b,t,e] ----------------
__global__ __launch_bounds__(256) void weighted_sum(const u16* __restrict__ ht,
                                                    const float* __restrict__ at,
                                                    float* __restrict__ out) {
  __shared__ float ats[512];
  int bx = blockIdx.x;                 // 256 blocks: b(32) x ec(2) x tc(4)
  int b = bx >> 3, sub = bx & 7, ec = sub & 1, tc = sub >> 1;
  for (int i = threadIdx.x; i < 512; i += 256) ats[i] = at[b * Tt + tc * 512 + i];
  __syncthreads();
  int e = ec * 512 + threadIdx.x * 2;
  const u16* base = ht + (size_t)(b * Tt + tc * 512) * Ee + e;
  float s0 = 0.f, s1 = 0.f;
  for (int tt = 0; tt < 512; ++tt) {
    float a = ats[tt];
    u32 u = *(const u32*)(base + (size_t)tt * Ee);
    s0 += a * __uint_as_float(u << 16);
    s1 += a * __uint_as_float(u & 0xffff0000u);
  }
  atomicAdd(&out[b * Ee + e], s0);
  atomicAdd(&out[b * Ee + e + 1], s1);
}

extern "C" void kernel_launch(void* const* d_in, const int* in_sizes, int n_in,
                              void* d_out, int out_size, void* d_ws, size_t ws_size,
                              hipStream_t stream) {
  const float* enc  = (const float*)d_in[0];
  const float* ctx  = (const float*)d_in[1];
  const float* W    = (const float*)d_in[2];
  const float* bias = (const float*)d_in[3];
  float* out = (float*)d_out;

  char* ws = (char*)d_ws;
  u16* Wt_hi = (u16*)(ws);
  u16* Wt_lo = (u16*)(ws + (size_t)2 * 1024 * 1024);
  u16* ht    = (u16*)(ws + (size_t)4 * 1024 * 1024);
  float* scores = (float*)(ws + (size_t)4 * 1024 * 1024 + (size_t)Mm * Ee * 2);
  float* at     = scores + Mm;
  // total ws use: 4 MB + 128 MB + 0.5 MB

  hipMemsetAsync(scores, 0, (size_t)Mm * sizeof(float), stream);
  hipMemsetAsync(out, 0, (size_t)Bb * Ee * sizeof(float), stream);

  wt_convert<<<dim3(32, 32), dim3(32, 8), 0, stream>>>(W, Wt_hi, Wt_lo);
  gemm_tanh_score<<<dim3(4096), dim3(256), 0, stream>>>(enc, ctx, bias, Wt_hi, Wt_lo, ht, scores);
  softmax_t<<<dim3(32), dim3(256), 0, stream>>>(scores, at);
  weighted_sum<<<dim3(256), dim3(256), 0, stream>>>(ht, at, out);
}

// Round 2
// 716.490 us; speedup vs baseline: 1.0770x; 1.0770x over previous
//
#include <hip/hip_runtime.h>
#include <hip/hip_bf16.h>
#include <math.h>

typedef unsigned short u16;
typedef unsigned int   u32;
typedef _Float16 f16x8 __attribute__((ext_vector_type(8)));
typedef float f32x4  __attribute__((ext_vector_type(4)));

#define Bb 32
#define Tt 2048
#define Ee 1024
#define Mm (Bb*Tt)
// LDS row stride in u16 elements (80 bytes): 16B-aligned frag reads, 2-way
// bank aliasing only (free per m136).
#define LSTR 40

__device__ __forceinline__ float tanh_fast(float x) {
  float ax = fminf(fabsf(x), 15.0f);
  float e  = __expf(2.0f * ax);
  float t  = 1.0f - 2.0f / (e + 1.0f);
  return copysignf(t, x);
}

__device__ __forceinline__ u32 pack2h(float a, float b) {
  _Float16 ha = (_Float16)a, hb = (_Float16)b;   // v_cvt_f16_f32 (RTN)
  return (u32)__builtin_bit_cast(u16, ha) | ((u32)__builtin_bit_cast(u16, hb) << 16);
}

// ---------------- K0: W (K x N fp32) -> Wt_hi/Wt_lo (N x K fp16 split) ----------------
__global__ __launch_bounds__(256) void wt_convert(const float* __restrict__ W,
                                                  u16* __restrict__ Wt_hi,
                                                  u16* __restrict__ Wt_lo) {
  __shared__ float tile[32][33];
  int n0 = blockIdx.x * 32, k0 = blockIdx.y * 32;
  int tx = threadIdx.x, ty = threadIdx.y;   // 32 x 8
#pragma unroll
  for (int i = 0; i < 4; ++i)
    tile[ty + 8*i][tx] = W[(size_t)(k0 + ty + 8*i) * Ee + n0 + tx];
  __syncthreads();
#pragma unroll
  for (int i = 0; i < 4; ++i) {
    float v = tile[tx][ty + 8*i];
    _Float16 hi = (_Float16)v;
    float rem = v - (float)hi;
    _Float16 lo = (_Float16)rem;
    size_t idx = (size_t)(n0 + ty + 8*i) * Ee + k0 + tx;
    Wt_hi[idx] = __builtin_bit_cast(u16, hi);
    Wt_lo[idx] = __builtin_bit_cast(u16, lo);
  }
}

// ---------------- K1: ht = tanh(enc@W + b), fused score = ctx . ht ----------------
// 128x128 tile, BK=32, 4 waves x (4x4 of mfma_f32_16x16x32_f16),
// 2-pass: acc += A_f16 * Whi + A_f16 * Wlo   (W split exact to ~2^-21)
__global__ __launch_bounds__(256, 2) void gemm_tanh_score(
    const float* __restrict__ enc, const float* __restrict__ ctx,
    const float* __restrict__ bias,
    const u16* __restrict__ Wt_hi, const u16* __restrict__ Wt_lo,
    u16* __restrict__ ht, float* __restrict__ scores) {
  __shared__ u16 Ahf[128*LSTR], Bhi[128*LSTR], Blo[128*LSTR];   // 30 KB

  int bx = blockIdx.x;
  int nt = bx & 7, mt = bx >> 3;        // consecutive blocks share the M-panel (L3 reuse of enc)
  int m0 = mt * 128, n0 = nt * 128;
  int tid = threadIdx.x;
  int w = tid >> 6, lane = tid & 63;
  int wm = (w & 1) * 64, wn = (w >> 1) * 64;
  int q = lane >> 4, c = lane & 15;

  f32x4 zero = {0.f, 0.f, 0.f, 0.f};
  f32x4 acc[4][4];
#pragma unroll
  for (int i = 0; i < 4; ++i)
#pragma unroll
    for (int j = 0; j < 4; ++j) acc[i][j] = zero;

  // staging mapping: thread t -> row (t>>1) in [0,128), k-half (t&1)*16
  int ar = tid >> 1, ah = tid & 1;
  const float* Ap  = enc   + (size_t)(m0 + ar) * Ee + ah * 16;
  const u16*   BhP = Wt_hi + (size_t)(n0 + ar) * Ee + ah * 16;
  const u16*   BlP = Wt_lo + (size_t)(n0 + ar) * Ee + ah * 16;
  u16* AW  = &Ahf[ar * LSTR + ah * 16];
  u16* BhW = &Bhi[ar * LSTR + ah * 16];
  u16* BlW = &Blo[ar * LSTR + ah * 16];

  for (int kt = 0; kt < 32; ++kt) {
    // global prefetch into registers (independent of LDS)
    const float4* ap = (const float4*)(Ap + (size_t)kt * 32);
    float4 f0 = ap[0], f1 = ap[1], f2 = ap[2], f3 = ap[3];
    const uint4* bhp = (const uint4*)(BhP + (size_t)kt * 32);
    uint4 bH0 = bhp[0], bH1 = bhp[1];
    const uint4* blp = (const uint4*)(BlP + (size_t)kt * 32);
    uint4 bL0 = blp[0], bL1 = blp[1];

    u32 a01 = pack2h(f0.x, f0.y), a23 = pack2h(f0.z, f0.w);
    u32 a45 = pack2h(f1.x, f1.y), a67 = pack2h(f1.z, f1.w);
    u32 a89 = pack2h(f2.x, f2.y), aAB = pack2h(f2.z, f2.w);
    u32 aCD = pack2h(f3.x, f3.y), aEF = pack2h(f3.z, f3.w);

    __syncthreads();   // previous iteration's frag reads complete
    ((uint4*)AW)[0]  = make_uint4(a01, a23, a45, a67);
    ((uint4*)AW)[1]  = make_uint4(a89, aAB, aCD, aEF);
    ((uint4*)BhW)[0] = bH0; ((uint4*)BhW)[1] = bH1;
    ((uint4*)BlW)[0] = bL0; ((uint4*)BlW)[1] = bL1;
    __syncthreads();   // staging visible

    f16x8 aF[4], bH[4], bL[4];
#pragma unroll
    for (int i = 0; i < 4; ++i) {
      int rax = (wm + i * 16 + c) * LSTR + q * 8;
      aF[i] = *(const f16x8*)(&Ahf[rax]);
      int rbx = (wn + i * 16 + c) * LSTR + q * 8;
      bH[i] = *(const f16x8*)(&Bhi[rbx]);
      bL[i] = *(const f16x8*)(&Blo[rbx]);
    }
#pragma unroll
    for (int i = 0; i < 4; ++i)
#pragma unroll
      for (int j = 0; j < 4; ++j) {
        acc[i][j] = __builtin_amdgcn_mfma_f32_16x16x32_f16(aF[i], bH[j], acc[i][j], 0, 0, 0);
        acc[i][j] = __builtin_amdgcn_mfma_f32_16x16x32_f16(aF[i], bL[j], acc[i][j], 0, 0, 0);
      }
  }

  // epilogue: z -> tanh -> store bf16 ht; fused score partial (ctx dot)
  int bidx = m0 >> 11;                   // T = 2048, tile rows share one batch index
  float ctxv[4], biasv[4];
#pragma unroll
  for (int j = 0; j < 4; ++j) {
    int col = n0 + wn + j * 16 + c;
    ctxv[j]  = ctx[bidx * Ee + col];
    biasv[j] = bias[col];
  }
#pragma unroll
  for (int i = 0; i < 4; ++i) {
#pragma unroll
    for (int r = 0; r < 4; ++r) {
      int rowG = m0 + wm + i * 16 + q * 4 + r;   // C/D: row=(lane>>4)*4+reg, col=lane&15
      u16* hrow = ht + (size_t)rowG * Ee + n0 + wn + c;
      float s = 0.f;
#pragma unroll
      for (int j = 0; j < 4; ++j) {
        float h = tanh_fast(acc[i][j][r] + biasv[j]);
        __hip_bfloat16 hb = __float2bfloat16(h);
        hrow[j * 16] = *(u16*)&hb;
        s += h * ctxv[j];
      }
      s += __shfl_xor(s, 1); s += __shfl_xor(s, 2);
      s += __shfl_xor(s, 4); s += __shfl_xor(s, 8);
      if (c == 0) atomicAdd(&scores[rowG], s);
    }
  }
}

// ---------------- K2: softmax over T per batch row ----------------
__global__ __launch_bounds__(256) void softmax_t(const float* __restrict__ scores,
                                                 float* __restrict__ at) {
  __shared__ float red[256];
  int b = blockIdx.x, tid = threadIdx.x;
  float v[8];
  float mx = -3.0e38f;
#pragma unroll
  for (int i = 0; i < 8; ++i) {
    v[i] = scores[b * Tt + i * 256 + tid];
    mx = fmaxf(mx, v[i]);
  }
  red[tid] = mx; __syncthreads();
  for (int s = 128; s > 0; s >>= 1) {
    if (tid < s) red[tid] = fmaxf(red[tid], red[tid + s]);
    __syncthreads();
  }
  mx = red[0]; __syncthreads();
  float sum = 0.f;
#pragma unroll
  for (int i = 0; i < 8; ++i) { v[i] = __expf(v[i] - mx); sum += v[i]; }
  red[tid] = sum; __syncthreads();
  for (int s = 128; s > 0; s >>= 1) {
    if (tid < s) red[tid] += red[tid + s];
    __syncthreads();
  }
  float inv = 1.0f / red[0];
#pragma unroll
  for (int i = 0; i < 8; ++i) at[b * Tt + i * 256 + tid] = v[i] * inv;
}

// ---------------- K3: partial[b,tc,e] = sum_{t in chunk} at[b,t] * ht[b,t,e] ----------------
// 1024 blocks (32 b x 32 t-chunks of 64), 256 thr, 4 e-cols/thread, fully coalesced rows.
__global__ __launch_bounds__(256) void weighted_sum(const u16* __restrict__ ht,
                                                    const float* __restrict__ at,
                                                    float* __restrict__ part) {
  __shared__ float ats[64];
  int bx = blockIdx.x;
  int b = bx >> 5, tc = bx & 31;
  int tid = threadIdx.x;
  if (tid < 64) ats[tid] = at[b * Tt + tc * 64 + tid];
  __syncthreads();
  int e0 = tid * 4;
  const u16* base = ht + (size_t)(b * Tt + tc * 64) * Ee + e0;
  float s0 = 0.f, s1 = 0.f, s2 = 0.f, s3 = 0.f;
#pragma unroll 4
  for (int t = 0; t < 64; ++t) {
    float a = ats[t];
    uint2 u = *(const uint2*)(base + (size_t)t * Ee);
    s0 += a * __uint_as_float(u.x << 16);
    s1 += a * __uint_as_float(u.x & 0xffff0000u);
    s2 += a * __uint_as_float(u.y << 16);
    s3 += a * __uint_as_float(u.y & 0xffff0000u);
  }
  float4 out4 = make_float4(s0, s1, s2, s3);
  *(float4*)(part + ((size_t)(b * 32 + tc) * Ee + e0)) = out4;
}

// ---------------- K4: out[b,e] = sum_tc part[b,tc,e] ----------------
__global__ __launch_bounds__(256) void reduce_part(const float* __restrict__ part,
                                                   float* __restrict__ out) {
  int b = blockIdx.x, tid = threadIdx.x;
  float4 s = make_float4(0.f, 0.f, 0.f, 0.f);
#pragma unroll
  for (int tc = 0; tc < 32; ++tc) {
    float4 p = ((const float4*)(part + (size_t)(b * 32 + tc) * Ee))[tid];
    s.x += p.x; s.y += p.y; s.z += p.z; s.w += p.w;
  }
  ((float4*)(out + (size_t)b * Ee))[tid] = s;
}

extern "C" void kernel_launch(void* const* d_in, const int* in_sizes, int n_in,
                              void* d_out, int out_size, void* d_ws, size_t ws_size,
                              hipStream_t stream) {
  const float* enc  = (const float*)d_in[0];
  const float* ctx  = (const float*)d_in[1];
  const float* W    = (const float*)d_in[2];
  const float* bias = (const float*)d_in[3];
  float* out = (float*)d_out;

  char* ws = (char*)d_ws;
  u16* Wt_hi = (u16*)(ws);
  u16* Wt_lo = (u16*)(ws + (size_t)2 * 1024 * 1024);
  u16* ht    = (u16*)(ws + (size_t)4 * 1024 * 1024);
  float* scores = (float*)(ws + (size_t)4 * 1024 * 1024 + (size_t)Mm * Ee * 2);
  float* at     = scores + Mm;
  // part reuses the Wt region (dead after the GEMM): 32*32*1024 fp32 = 4 MB
  float* part   = (float*)ws;
  // total ws use: max(4 MB Wt planes, 4 MB part) + 128 MB ht + 0.5 MB scores/at

  hipMemsetAsync(scores, 0, (size_t)Mm * sizeof(float), stream);

  wt_convert<<<dim3(32, 32), dim3(32, 8), 0, stream>>>(W, Wt_hi, Wt_lo);
  gemm_tanh_score<<<dim3(4096), dim3(256), 0, stream>>>(enc, ctx, bias, Wt_hi, Wt_lo, ht, scores);
  softmax_t<<<dim3(32), dim3(256), 0, stream>>>(scores, at);
  weighted_sum<<<dim3(1024), dim3(256), 0, stream>>>(ht, at, part);
  reduce_part<<<dim3(32), dim3(256), 0, stream>>>(part, out);
}